// Round 1
// baseline (18861.186 us; speedup 1.0000x reference)
//
#include <hip/hip_runtime.h>
#include <stdint.h>

typedef unsigned short u16;
typedef unsigned int   u32;

// Problem dims
#define T_STEPS 256
#define B_TOT   512
#define EDIM    256
#define HDIM    256
#define CDIM    256
#define NSLOT   128
#define VDIM    256
#define ODIM    256

// bf16-packed weight layout inside d_ws (u16 units)
#define OFF_W1 0         // 512x256
#define OFF_W2 131072    // 256x256
#define OFF_WR 196608    // 256x256
#define OFF_WW 262144    // 256x512
#define OFF_WO 393216    // 512x256
#define W_TOTAL 524288

// LDS mem layout: per b-row: 128 slots x 264 u16 (256 data + 8 pad) => 33 uint4/slot
// pad makes bank-group = (33*n + q) & 7 uniform across a wave for b128 ops.
#define USLOT 264
#define QSLOT 33
#define US_B  (NSLOT * USLOT)     // 33792 u16 per b
#define Q_B   (NSLOT * QSLOT)     // 4224 uint4 per b
#define DLDS  (2 * US_B * 2)      // 135168 bytes dynamic LDS

__device__ __forceinline__ float bflo(u32 u) { return __uint_as_float(u << 16); }
__device__ __forceinline__ float bfhi(u32 u) { return __uint_as_float(u & 0xffff0000u); }
__device__ __forceinline__ u32 f2bfbits(float f) {
    u32 a = __float_as_uint(f);
    return (a + 0x7fffu + ((a >> 16) & 1u)) >> 16;   // RNE
}
__device__ __forceinline__ u32 pkbf(float lo, float hi) {
    u32 a = __float_as_uint(lo), b = __float_as_uint(hi);
    a = a + 0x7fffu + ((a >> 16) & 1u);
    b = b + 0x7fffu + ((b >> 16) & 1u);
    return (a >> 16) | (b & 0xffff0000u);
}

// weight fp32 -> bf16 prep (runs every call; ws is re-poisoned by harness)
__global__ void cvt_weights(const float* __restrict__ W1, const float* __restrict__ W2,
                            const float* __restrict__ Wr, const float* __restrict__ Ww,
                            const float* __restrict__ Wo, u16* __restrict__ dst) {
    int idx = blockIdx.x * 256 + threadIdx.x;
    float v;
    if      (idx < 131072) v = W1[idx];
    else if (idx < 196608) v = W2[idx - 131072];
    else if (idx < 262144) v = Wr[idx - 196608];
    else if (idx < 393216) v = Ww[idx - 262144];
    else                   v = Wo[idx - 393216];
    dst[idx] = (u16)f2bfbits(v);
}

// Batched 2-row matvec: dst = src(2xK) @ W(KxC) + bias, optional relu.
// src LDS layout: [k*2 + row] fp32. Weights bf16 row-major.
// Thread map: jg = tid % (C/8) owns 8 cols; s = tid / (C/8) owns K-slice.
// Reduction: s==0 writes raw(+bias), others atomicAdd (LDS ds_add_f32).
// DST: 0 = LDS fp32 interleaved [c*2+row]; 1 = LDS bf16 flat [row*C+c]; 2 = global out
template<int K, int C, int DST, bool RELU>
__device__ __forceinline__ void matvec(const u16* __restrict__ W,
                                       const float* __restrict__ src,
                                       const float* __restrict__ bias,
                                       float* __restrict__ raw,
                                       float* __restrict__ dstF,
                                       u16* __restrict__ dstB,
                                       float* __restrict__ gout) {
    constexpr int G8  = C / 8;
    constexpr int S   = 512 / G8;
    constexpr int LEN = K / S;
    const int tid = threadIdx.x;
    const int jg  = tid & (G8 - 1);
    const int s   = tid / G8;
    const int k0  = s * LEN;

    float a0[8], a1[8];
#pragma unroll
    for (int j = 0; j < 8; ++j) { a0[j] = 0.f; a1[j] = 0.f; }

    float bj[8];
    if (s == 0) {
#pragma unroll
        for (int j = 0; j < 8; ++j) bj[j] = bias[jg * 8 + j];
    }

    const uint4*  Wq = reinterpret_cast<const uint4*>(W) + (size_t)k0 * G8 + jg;
    const float4* s4 = reinterpret_cast<const float4*>(src) + (k0 >> 1);

#pragma unroll 4
    for (int kk = 0; kk < LEN; kk += 2) {
        const uint4 wa = Wq[(kk) * G8];
        const uint4 wb = Wq[(kk + 1) * G8];
        const float4 cc = s4[kk >> 1];
        const u32* pa = reinterpret_cast<const u32*>(&wa);
        const u32* pb = reinterpret_cast<const u32*>(&wb);
#pragma unroll
        for (int q = 0; q < 4; ++q) {
            float f0 = bflo(pa[q]), f1 = bfhi(pa[q]);
            a0[2*q  ] = fmaf(cc.x, f0, a0[2*q  ]);
            a1[2*q  ] = fmaf(cc.y, f0, a1[2*q  ]);
            a0[2*q+1] = fmaf(cc.x, f1, a0[2*q+1]);
            a1[2*q+1] = fmaf(cc.y, f1, a1[2*q+1]);
            float g0 = bflo(pb[q]), g1 = bfhi(pb[q]);
            a0[2*q  ] = fmaf(cc.z, g0, a0[2*q  ]);
            a1[2*q  ] = fmaf(cc.w, g0, a1[2*q  ]);
            a0[2*q+1] = fmaf(cc.z, g1, a0[2*q+1]);
            a1[2*q+1] = fmaf(cc.w, g1, a1[2*q+1]);
        }
    }

    if (s == 0) {
#pragma unroll
        for (int j = 0; j < 8; ++j) {
            int c2 = (jg * 8 + j) * 2;
            raw[c2]     = a0[j] + bj[j];
            raw[c2 + 1] = a1[j] + bj[j];
        }
    }
    __syncthreads();
    if (s != 0) {
#pragma unroll
        for (int j = 0; j < 8; ++j) {
            int c2 = (jg * 8 + j) * 2;
            atomicAdd(&raw[c2],     a0[j]);
            atomicAdd(&raw[c2 + 1], a1[j]);
        }
    }
    __syncthreads();
#pragma unroll
    for (int idx = tid; idx < C * 2; idx += 512) {
        float v = raw[idx];
        if (RELU) v = fmaxf(v, 0.0f);
        int c = idx >> 1, row = idx & 1;
        if constexpr (DST == 0) dstF[idx] = v;
        else if constexpr (DST == 1) dstB[row * C + c] = (u16)f2bfbits(v);
        else gout[row * ODIM + c] = v;
    }
    __syncthreads();
}

__global__ __launch_bounds__(512, 1)
void ntm_main(const float* __restrict__ x, const u16* __restrict__ Wb,
              const float* __restrict__ b1, const float* __restrict__ b2,
              const float* __restrict__ br, const float* __restrict__ bw,
              const float* __restrict__ bo,
              const float* __restrict__ init_read, const float* __restrict__ mem0,
              float* __restrict__ out) {
    extern __shared__ u16 s_mem[];                 // 2 x 128 x 264 bf16, padded
    __shared__ __align__(16) float s_ci[1024];     // [xt | r] interleaved [k*2+row]
    __shared__ __align__(16) float s_h[512];       // h interleaved
    __shared__ __align__(16) float s_cr[1024];     // [co | r] interleaved (Wo input)
    __shared__ __align__(16) float s_raw[1024];    // matvec reduction buffer
    __shared__ __align__(16) u16   s_kvb[512];     // k, bf16 flat [row*256+c]
    __shared__ __align__(16) u16   s_ovb[1024];    // [kw | v], bf16 flat [row*512+c]
    __shared__ __align__(16) float s_dotr[256], s_dotw[256], s_mn2[256];
    __shared__ __align__(16) float s_wr[256], s_ww[256];

    const int tid = threadIdx.x;
    const int b0  = blockIdx.x * 2;
    uint4* memq = reinterpret_cast<uint4*>(s_mem);

    // ---- init: mem0 -> LDS bf16 (padded layout), init_read -> ci r-slot ----
#pragma unroll 1
    for (int it = 0; it < 128; ++it) {
        int idx = it * 512 + tid;            // 0..65535
        int row = idx >> 15, rem = idx & 32767;
        int n = rem >> 8, v = rem & 255;
        float g = mem0[((size_t)(b0 + row) << 15) + rem];
        s_mem[row * US_B + n * USLOT + v] = (u16)f2bfbits(g);
    }
    {
        int row = tid >> 8, j = tid & 255;
        s_ci[(256 + j) * 2 + row] = init_read[(size_t)(b0 + row) * 256 + j];
    }
    __syncthreads();

#pragma unroll 1
    for (int t = 0; t < T_STEPS; ++t) {
        // ---- load x_t ----
        {
            int row = tid >> 8, e = tid & 255;
            s_ci[e * 2 + row] = x[(size_t)t * (B_TOT * EDIM) + (size_t)(b0 + row) * EDIM + e];
        }
        __syncthreads();

        // ---- GEMM chain ----
        matvec<512, 256, 0, true >(Wb + OFF_W1, s_ci, b1, s_raw, s_h,  nullptr, nullptr);
        matvec<256, 256, 0, false>(Wb + OFF_W2, s_h,  b2, s_raw, s_cr, nullptr, nullptr);
        matvec<256, 256, 1, false>(Wb + OFF_WR, s_cr, br, s_raw, nullptr, s_kvb, nullptr);
        matvec<256, 512, 1, false>(Wb + OFF_WW, s_cr, bw, s_raw, nullptr, s_ovb, nullptr);

        // ---- pass1: dots (k.mem, kw.mem) + slot norms; thread = (row, n, vhalf) ----
        {
            const int row = tid >> 8, t8 = tid & 255;
            const int n = t8 >> 1, vh = t8 & 1;
            const uint4* mq  = memq + row * Q_B + n * QSLOT + vh * 16;
            const uint4* kq  = reinterpret_cast<const uint4*>(s_kvb) + row * 32 + vh * 16;
            const uint4* kwq = reinterpret_cast<const uint4*>(s_ovb) + row * 64 + vh * 16;
            float dr = 0.f, dw = 0.f, s2 = 0.f;
#pragma unroll 4
            for (int i = 0; i < 16; ++i) {
                uint4 m = mq[i], ka = kq[i], kb = kwq[i];
                const u32* pm = reinterpret_cast<const u32*>(&m);
                const u32* pk = reinterpret_cast<const u32*>(&ka);
                const u32* pw = reinterpret_cast<const u32*>(&kb);
#pragma unroll
                for (int q = 0; q < 4; ++q) {
                    float m0 = bflo(pm[q]), m1 = bfhi(pm[q]);
                    float k0v = bflo(pk[q]), k1v = bfhi(pk[q]);
                    float w0 = bflo(pw[q]), w1 = bfhi(pw[q]);
                    dr = fmaf(m0, k0v, dr); dr = fmaf(m1, k1v, dr);
                    dw = fmaf(m0, w0, dw);  dw = fmaf(m1, w1, dw);
                    s2 = fmaf(m0, m0, s2);  s2 = fmaf(m1, m1, s2);
                }
            }
            dr += __shfl_xor(dr, 1);
            dw += __shfl_xor(dw, 1);
            s2 += __shfl_xor(s2, 1);
            if (vh == 0) {
                s_dotr[row * 128 + n] = dr;
                s_dotw[row * 128 + n] = dw;
                s_mn2[row * 128 + n]  = s2;
            }
        }
        __syncthreads();

        // ---- softmax (cosine addressing), one wave per (row,key) ----
        if (tid < 256) {
            const int combo = tid >> 6;
            const int row = combo >> 1, key = combo & 1;
            const int lane = tid & 63;
            const uint2* kv2 = key ? (reinterpret_cast<const uint2*>(s_ovb) + row * 128)
                                   : (reinterpret_cast<const uint2*>(s_kvb) + row * 64);
            uint2 kk = kv2[lane];
            float q0 = bflo(kk.x), q1 = bfhi(kk.x), q2 = bflo(kk.y), q3 = bfhi(kk.y);
            float q = q0*q0 + q1*q1 + q2*q2 + q3*q3;
#pragma unroll
            for (int m = 1; m < 64; m <<= 1) q += __shfl_xor(q, m);
            float kn = fmaxf(sqrtf(q), 1e-8f);
            const float* dot = key ? s_dotw : s_dotr;
            int n0 = lane, n1 = lane + 64;
            float mn0 = fmaxf(sqrtf(s_mn2[row * 128 + n0]), 1e-8f);
            float mn1 = fmaxf(sqrtf(s_mn2[row * 128 + n1]), 1e-8f);
            float av0 = dot[row * 128 + n0] / (kn * mn0);
            float av1 = dot[row * 128 + n1] / (kn * mn1);
            float mx = fmaxf(av0, av1);
#pragma unroll
            for (int m = 1; m < 64; m <<= 1) mx = fmaxf(mx, __shfl_xor(mx, m));
            float e0 = __expf(av0 - mx), e1 = __expf(av1 - mx);
            float sm = e0 + e1;
#pragma unroll
            for (int m = 1; m < 64; m <<= 1) sm += __shfl_xor(sm, m);
            float inv = 1.0f / sm;
            float* wdst = key ? s_ww : s_wr;
            wdst[row * 128 + n0] = e0 * inv;
            wdst[row * 128 + n1] = e1 * inv;
        }
        __syncthreads();

        // ---- pass2a: r = sum_n w[n] * mem[n,:]; thread = (row, ns(16n), v8(8v)) ----
        {
            const int row = tid >> 8, t8 = tid & 255;
            const int v8 = t8 & 31, ns = t8 >> 5;
            const float4* w4p = reinterpret_cast<const float4*>(s_wr + row * 128 + ns * 16);
            float4 wA = w4p[0], wB = w4p[1], wC = w4p[2], wD = w4p[3];
            float w[16] = {wA.x, wA.y, wA.z, wA.w, wB.x, wB.y, wB.z, wB.w,
                           wC.x, wC.y, wC.z, wC.w, wD.x, wD.y, wD.z, wD.w};
            float r[8];
#pragma unroll
            for (int j = 0; j < 8; ++j) r[j] = 0.f;
            const uint4* mq = memq + row * Q_B + (ns * 16) * QSLOT + v8;
#pragma unroll 4
            for (int nn = 0; nn < 16; ++nn) {
                uint4 m = mq[nn * QSLOT];
                const u32* pm = reinterpret_cast<const u32*>(&m);
                float wj = w[nn];
#pragma unroll
                for (int q = 0; q < 4; ++q) {
                    r[2*q  ] = fmaf(bflo(pm[q]), wj, r[2*q  ]);
                    r[2*q+1] = fmaf(bfhi(pm[q]), wj, r[2*q+1]);
                }
            }
            if (ns == 0) {
#pragma unroll
                for (int j = 0; j < 8; ++j) s_raw[(v8 * 8 + j) * 2 + row] = r[j];
            }
            __syncthreads();
            if (ns != 0) {
#pragma unroll
                for (int j = 0; j < 8; ++j) atomicAdd(&s_raw[(v8 * 8 + j) * 2 + row], r[j]);
            }
            __syncthreads();
            {   // r -> ci r-slot (next step input) and cr r-slot (Wo input)
                int c = tid >> 1, row2 = tid & 1;
                float val = s_raw[tid];
                s_ci[(256 + c) * 2 + row2] = val;
                s_cr[(256 + c) * 2 + row2] = val;
            }
            __syncthreads();
        }

        // ---- pass2b: mem += ww[n] * v ; thread = (row, n, vhalf) ----
        {
            const int row = tid >> 8, t8 = tid & 255;
            const int n = t8 >> 1, vh = t8 & 1;
            uint4* mq = memq + row * Q_B + n * QSLOT + vh * 16;
            const uint4* vvq = reinterpret_cast<const uint4*>(s_ovb) + row * 64 + 32 + vh * 16;
            const float ww = s_ww[row * 128 + n];
#pragma unroll 4
            for (int i = 0; i < 16; ++i) {
                uint4 m = mq[i], vv = vvq[i];
                u32* pm = reinterpret_cast<u32*>(&m);
                const u32* pv = reinterpret_cast<const u32*>(&vv);
#pragma unroll
                for (int q = 0; q < 4; ++q) {
                    float o0 = fmaf(bflo(pv[q]), ww, bflo(pm[q]));
                    float o1 = fmaf(bfhi(pv[q]), ww, bfhi(pm[q]));
                    pm[q] = pkbf(o0, o1);
                }
                mq[i] = m;
            }
        }
        __syncthreads();

        // ---- out_t = [co | r] @ Wo + bo -> global ----
        matvec<512, 256, 2, false>(Wb + OFF_WO, s_cr, bo, s_raw, nullptr, nullptr,
                                   out + (size_t)t * (B_TOT * ODIM) + (size_t)b0 * ODIM);
    }
}

extern "C" void kernel_launch(void* const* d_in, const int* in_sizes, int n_in,
                              void* d_out, int out_size, void* d_ws, size_t ws_size,
                              hipStream_t stream) {
    (void)in_sizes; (void)n_in; (void)out_size; (void)ws_size;
    const float* x         = (const float*)d_in[0];
    const float* W1        = (const float*)d_in[1];
    const float* b1        = (const float*)d_in[2];
    const float* W2        = (const float*)d_in[3];
    const float* b2        = (const float*)d_in[4];
    const float* Wr        = (const float*)d_in[5];
    const float* br        = (const float*)d_in[6];
    const float* Ww        = (const float*)d_in[7];
    const float* bw        = (const float*)d_in[8];
    const float* Wo        = (const float*)d_in[9];
    const float* bo        = (const float*)d_in[10];
    const float* init_read = (const float*)d_in[11];
    const float* mem0      = (const float*)d_in[12];
    float* out = (float*)d_out;
    u16* wb = (u16*)d_ws;

    hipLaunchKernelGGL(cvt_weights, dim3(W_TOTAL / 256), dim3(256), 0, stream,
                       W1, W2, Wr, Ww, Wo, wb);

    // opt-in to >64KB dynamic LDS (harmless if not required on ROCm)
    (void)hipFuncSetAttribute(reinterpret_cast<const void*>(ntm_main),
                              hipFuncAttributeMaxDynamicSharedMemorySize, DLDS);

    hipLaunchKernelGGL(ntm_main, dim3(B_TOT / 2), dim3(512), DLDS, stream,
                       x, wb, b1, b2, br, bw, bo, init_read, mem0, out);
}

// Round 4
// 9265.156 us; speedup vs baseline: 2.0357x; 2.0357x over previous
//
#include <hip/hip_runtime.h>
#include <stdint.h>

typedef unsigned short u16;
typedef unsigned int   u32;

// Problem dims
#define T_STEPS 256
#define B_TOT   512
#define EDIM    256
#define NSLOT   128
#define VDIM    256
#define ODIM    256

// bf16-packed weight layout inside d_ws (u16 units), row-major KxC
#define OFF_W1 0         // 512x256
#define OFF_W2 131072    // 256x256
#define OFF_WR 196608    // 256x256
#define OFF_WW 262144    // 256x512
#define OFF_WO 393216    // 512x256
#define W_TOTAL 524288

// LDS mem layout: per b-row: 128 slots x 264 u16 (256 data + 8 pad) => 33 uint4/slot
#define USLOT 264
#define QSLOT 33
#define US_B  (NSLOT * USLOT)     // 33792 u16 per b-row
#define Q_B   (NSLOT * QSLOT)     // 4224 uint4 per b-row
#define DLDS  (2 * US_B * 2)      // 135168 bytes dynamic LDS

__device__ __forceinline__ float bflo(u32 u) { return __uint_as_float(u << 16); }
__device__ __forceinline__ float bfhi(u32 u) { return __uint_as_float(u & 0xffff0000u); }
__device__ __forceinline__ u32 f2bfbits(float f) {
    u32 a = __float_as_uint(f);
    return (a + 0x7fffu + ((a >> 16) & 1u)) >> 16;   // RNE
}
__device__ __forceinline__ u32 pkbf(float lo, float hi) {
    u32 a = __float_as_uint(lo), b = __float_as_uint(hi);
    a = a + 0x7fffu + ((a >> 16) & 1u);
    b = b + 0x7fffu + ((b >> 16) & 1u);
    return (a >> 16) | (b & 0xffff0000u);
}

__global__ void cvt_weights(const float* __restrict__ W1, const float* __restrict__ W2,
                            const float* __restrict__ Wr, const float* __restrict__ Ww,
                            const float* __restrict__ Wo, u16* __restrict__ dst) {
    int idx = blockIdx.x * 256 + threadIdx.x;
    float v;
    if      (idx < 131072) v = W1[idx];
    else if (idx < 196608) v = W2[idx - 131072];
    else if (idx < 262144) v = Wr[idx - 196608];
    else if (idx < 393216) v = Ww[idx - 262144];
    else                   v = Wo[idx - 393216];
    dst[idx] = (u16)f2bfbits(v);
}

// 2-row matvec, 1024 threads. Thread owns 2 adjacent cols of 1 row, k-slice s.
// src planar fp32, row stride SROW (elements). W bf16 row-major KxC.
// Partials -> s_part, one barrier, finalize sums S partials. No LDS atomics.
// DROW = destination row stride. DST: 0 = LDS fp32; 1 = LDS bf16; 2 = global.
template<int K, int C, int SROW, int DROW, int DST, bool RELU>
__device__ __forceinline__ void matvec2(const u16* __restrict__ W,
                                        const float* __restrict__ src,
                                        const float* __restrict__ bias,
                                        float* __restrict__ part,
                                        float* __restrict__ dstF,
                                        u16* __restrict__ dstB,
                                        float* __restrict__ gout) {
    constexpr int G   = C / 2;            // col-pair groups (128 or 256)
    constexpr int LG  = (G == 128) ? 7 : 8;
    constexpr int S   = 1024 / (2 * G);   // k-slices (4 or 2)
    constexpr int LEN = K / S;
    constexpr int LC  = (C == 256) ? 8 : 9;
    const int tid = threadIdx.x;
    const int jg  = tid & (G - 1);
    const int row = (tid >> LG) & 1;
    const int s   = tid >> (LG + 1);

    float a0 = 0.f, a1 = 0.f;
    const u32*   Wp = reinterpret_cast<const u32*>(W) + (size_t)(s * LEN) * G + jg;
    const float* sp = src + row * SROW + s * LEN;

#pragma unroll 2
    for (int kk = 0; kk < LEN; kk += 8) {
        u32 w[8];
#pragma unroll
        for (int i = 0; i < 8; ++i) w[i] = Wp[(kk + i) * G];
        float4 c0 = *reinterpret_cast<const float4*>(sp + kk);
        float4 c1 = *reinterpret_cast<const float4*>(sp + kk + 4);
        float cs[8] = {c0.x, c0.y, c0.z, c0.w, c1.x, c1.y, c1.z, c1.w};
#pragma unroll
        for (int i = 0; i < 8; ++i) {
            a0 = fmaf(cs[i], bflo(w[i]), a0);
            a1 = fmaf(cs[i], bfhi(w[i]), a1);
        }
    }
    part[(s * 2 + row) * C + jg * 2]     = a0;
    part[(s * 2 + row) * C + jg * 2 + 1] = a1;
    __syncthreads();

    if (tid < 2 * C) {
        const int row2 = tid >> LC;
        const int c    = tid & (C - 1);
        float v = bias[c];
#pragma unroll
        for (int s2 = 0; s2 < S; ++s2) v += part[(s2 * 2 + row2) * C + c];
        if (RELU) v = fmaxf(v, 0.0f);
        if constexpr (DST == 0)      dstF[row2 * DROW + c] = v;
        else if constexpr (DST == 1) dstB[row2 * DROW + c] = (u16)f2bfbits(v);
        else                         gout[row2 * DROW + c] = v;
    }
    if constexpr (DST != 2) __syncthreads();
}

__global__ __launch_bounds__(1024, 4)
void ntm_main(const float* __restrict__ x, const u16* __restrict__ Wb,
              const float* __restrict__ b1, const float* __restrict__ b2,
              const float* __restrict__ br, const float* __restrict__ bw,
              const float* __restrict__ bo,
              const float* __restrict__ init_read, const float* __restrict__ mem0,
              float* __restrict__ out) {
    extern __shared__ u16 s_mem[];                 // 2 x 128 x 264 bf16 (padded)
    __shared__ __align__(16) float s_ci[1024];     // planar [row*512 + k]  (x | r)
    __shared__ __align__(16) float s_h[512];       // planar [row*256 + k]
    __shared__ __align__(16) float s_cr[1024];     // planar [row*512 + k]  (co | r)
    __shared__ __align__(16) float s_part[2048];   // matvec partials / r accum
    __shared__ __align__(16) u16   s_kvb[512];     // k bf16 planar [row*256+c]
    __shared__ __align__(16) u16   s_ovb[1024];    // [kw|v] bf16 planar [row*512+c]
    __shared__ __align__(16) float s_dotr[256], s_dotw[256], s_mn2[256];
    __shared__ __align__(16) float s_wr[256], s_ww[256];

    const int tid = threadIdx.x;
    const int b0  = blockIdx.x * 2;
    uint4* memq = reinterpret_cast<uint4*>(s_mem);

    // ---- init: mem0 -> LDS bf16 (padded), init_read -> ci r-slot ----
#pragma unroll 1
    for (int it = 0; it < 64; ++it) {
        int idx = it * 1024 + tid;           // 0..65535
        int row = idx >> 15, rem = idx & 32767;
        int n = rem >> 8, v = rem & 255;
        float g = mem0[((size_t)(b0 + row) << 15) + rem];
        s_mem[row * US_B + n * USLOT + v] = (u16)f2bfbits(g);
    }
    if (tid < 512) {
        int row = tid >> 8, j = tid & 255;
        s_ci[row * 512 + 256 + j] = init_read[(size_t)(b0 + row) * 256 + j];
    }
    __syncthreads();

#pragma unroll 1
    for (int t = 0; t < T_STEPS; ++t) {
        // ---- load x_t (planar) ----
        if (tid < 512) {
            int row = tid >> 8, e = tid & 255;
            s_ci[row * 512 + e] = x[(size_t)t * (B_TOT * EDIM) + (size_t)(b0 + row) * EDIM + e];
        }
        __syncthreads();

        // ---- GEMM chain ----
        matvec2<512, 256, 512, 256, 0, true >(Wb + OFF_W1, s_ci, b1, s_part, s_h,  nullptr, nullptr);
        matvec2<256, 256, 256, 512, 0, false>(Wb + OFF_W2, s_h,  b2, s_part, s_cr, nullptr, nullptr);
        matvec2<256, 256, 512, 256, 1, false>(Wb + OFF_WR, s_cr, br, s_part, nullptr, s_kvb, nullptr);
        matvec2<256, 512, 512, 512, 1, false>(Wb + OFF_WW, s_cr, bw, s_part, nullptr, s_ovb, nullptr);

        // ---- pass1: dots (k.mem, kw.mem) + slot norms; thread = (row, n, vq) ----
        {
            const int row = tid >> 9, t9 = tid & 511;
            const int n = t9 >> 2, vq = t9 & 3;     // vq: 64-elem chunk (8 uint4)
            const uint4* mq  = memq + row * Q_B + n * QSLOT + vq * 8;
            const uint4* kq  = reinterpret_cast<const uint4*>(s_kvb) + row * 32 + vq * 8;
            const uint4* kwq = reinterpret_cast<const uint4*>(s_ovb) + row * 64 + vq * 8;
            float dr = 0.f, dw = 0.f, s2 = 0.f;
#pragma unroll
            for (int i = 0; i < 8; ++i) {
                uint4 m = mq[i], ka = kq[i], kb = kwq[i];
                const u32* pm = reinterpret_cast<const u32*>(&m);
                const u32* pk = reinterpret_cast<const u32*>(&ka);
                const u32* pw = reinterpret_cast<const u32*>(&kb);
#pragma unroll
                for (int q = 0; q < 4; ++q) {
                    float m0 = bflo(pm[q]), m1 = bfhi(pm[q]);
                    float k0v = bflo(pk[q]), k1v = bfhi(pk[q]);
                    float w0 = bflo(pw[q]), w1 = bfhi(pw[q]);
                    dr = fmaf(m0, k0v, dr); dr = fmaf(m1, k1v, dr);
                    dw = fmaf(m0, w0, dw);  dw = fmaf(m1, w1, dw);
                    s2 = fmaf(m0, m0, s2);  s2 = fmaf(m1, m1, s2);
                }
            }
            dr += __shfl_xor(dr, 1); dr += __shfl_xor(dr, 2);
            dw += __shfl_xor(dw, 1); dw += __shfl_xor(dw, 2);
            s2 += __shfl_xor(s2, 1); s2 += __shfl_xor(s2, 2);
            if (vq == 0) {
                s_dotr[row * 128 + n] = dr;
                s_dotw[row * 128 + n] = dw;
                s_mn2[row * 128 + n]  = s2;
            }
        }
        __syncthreads();

        // ---- softmax (cosine addressing), one wave per (row,key) ----
        if (tid < 256) {
            const int combo = tid >> 6;
            const int row = combo >> 1, key = combo & 1;
            const int lane = tid & 63;
            const uint2* kv2 = key ? (reinterpret_cast<const uint2*>(s_ovb) + row * 128)
                                   : (reinterpret_cast<const uint2*>(s_kvb) + row * 64);
            uint2 kk = kv2[lane];
            float q0 = bflo(kk.x), q1 = bfhi(kk.x), q2 = bflo(kk.y), q3 = bfhi(kk.y);
            float q = q0*q0 + q1*q1 + q2*q2 + q3*q3;
#pragma unroll
            for (int m = 1; m < 64; m <<= 1) q += __shfl_xor(q, m);
            float kn = fmaxf(sqrtf(q), 1e-8f);
            const float* dot = key ? s_dotw : s_dotr;
            int n0 = lane, n1 = lane + 64;
            float mn0 = fmaxf(sqrtf(s_mn2[row * 128 + n0]), 1e-8f);
            float mn1 = fmaxf(sqrtf(s_mn2[row * 128 + n1]), 1e-8f);
            float av0 = dot[row * 128 + n0] / (kn * mn0);
            float av1 = dot[row * 128 + n1] / (kn * mn1);
            float mx = fmaxf(av0, av1);
#pragma unroll
            for (int m = 1; m < 64; m <<= 1) mx = fmaxf(mx, __shfl_xor(mx, m));
            float e0 = __expf(av0 - mx), e1 = __expf(av1 - mx);
            float sm = e0 + e1;
#pragma unroll
            for (int m = 1; m < 64; m <<= 1) sm += __shfl_xor(sm, m);
            float inv = 1.0f / sm;
            float* wdst = key ? s_ww : s_wr;
            wdst[row * 128 + n0] = e0 * inv;
            wdst[row * 128 + n1] = e1 * inv;
        }
        __syncthreads();

        // ---- pass2a: r = sum_n w[n]*mem[n,:]; thread = (row, ns(8 slots), v8) ----
        {
            const int row = tid >> 9, t9 = tid & 511;
            const int ns = t9 >> 5, v8 = t9 & 31;   // v8: 8-elem chunk (1 uint4)
            float r[8];
#pragma unroll
            for (int j = 0; j < 8; ++j) r[j] = 0.f;
            const uint4* mq = memq + row * Q_B + (ns * 8) * QSLOT + v8;
            const float* wp = s_wr + row * 128 + ns * 8;
#pragma unroll
            for (int j = 0; j < 8; ++j) {
                uint4 m = mq[j * QSLOT];
                const u32* pm = reinterpret_cast<const u32*>(&m);
                float wj = wp[j];
#pragma unroll
                for (int q = 0; q < 4; ++q) {
                    r[2*q  ] = fmaf(bflo(pm[q]), wj, r[2*q  ]);
                    r[2*q+1] = fmaf(bfhi(pm[q]), wj, r[2*q+1]);
                }
            }
            if (ns == 0) {
#pragma unroll
                for (int j = 0; j < 8; ++j) s_part[row * 256 + v8 * 8 + j] = r[j];
            }
            __syncthreads();
            if (ns != 0) {
#pragma unroll
                for (int j = 0; j < 8; ++j) atomicAdd(&s_part[row * 256 + v8 * 8 + j], r[j]);
            }
            __syncthreads();
        }
        // r -> ci r-slot and cr r-slot
        if (tid < 512) {
            int row = tid >> 8, c = tid & 255;
            float val = s_part[row * 256 + c];
            s_ci[row * 512 + 256 + c] = val;
            s_cr[row * 512 + 256 + c] = val;
        }

        // ---- pass2b: mem += ww[n]*v ; thread = (row, n, vq) ----
        {
            const int row = tid >> 9, t9 = tid & 511;
            const int n = t9 >> 2, vq = t9 & 3;
            uint4* mq = memq + row * Q_B + n * QSLOT + vq * 8;
            const uint4* vvq = reinterpret_cast<const uint4*>(s_ovb) + row * 64 + 32 + vq * 8;
            const float ww = s_ww[row * 128 + n];
#pragma unroll
            for (int i = 0; i < 8; ++i) {
                uint4 m = mq[i], vv = vvq[i];
                u32* pm = reinterpret_cast<u32*>(&m);
                const u32* pv = reinterpret_cast<const u32*>(&vv);
#pragma unroll
                for (int q = 0; q < 4; ++q) {
                    float o0 = fmaf(bflo(pv[q]), ww, bflo(pm[q]));
                    float o1 = fmaf(bfhi(pv[q]), ww, bfhi(pm[q]));
                    pm[q] = pkbf(o0, o1);
                }
                mq[i] = m;
            }
        }
        __syncthreads();

        // ---- out_t = [co | r] @ Wo + bo -> global ----
        matvec2<512, 256, 512, 256, 2, false>(Wb + OFF_WO, s_cr, bo, s_part, nullptr, nullptr,
                                              out + (size_t)t * (B_TOT * ODIM) + (size_t)b0 * ODIM);
    }
}

extern "C" void kernel_launch(void* const* d_in, const int* in_sizes, int n_in,
                              void* d_out, int out_size, void* d_ws, size_t ws_size,
                              hipStream_t stream) {
    (void)in_sizes; (void)n_in; (void)out_size; (void)ws_size;
    const float* x         = (const float*)d_in[0];
    const float* W1        = (const float*)d_in[1];
    const float* b1        = (const float*)d_in[2];
    const float* W2        = (const float*)d_in[3];
    const float* b2        = (const float*)d_in[4];
    const float* Wr        = (const float*)d_in[5];
    const float* br        = (const float*)d_in[6];
    const float* Ww        = (const float*)d_in[7];
    const float* bw        = (const float*)d_in[8];
    const float* Wo        = (const float*)d_in[9];
    const float* bo        = (const float*)d_in[10];
    const float* init_read = (const float*)d_in[11];
    const float* mem0      = (const float*)d_in[12];
    float* out = (float*)d_out;
    u16* wb = (u16*)d_ws;

    hipLaunchKernelGGL(cvt_weights, dim3(W_TOTAL / 256), dim3(256), 0, stream,
                       W1, W2, Wr, Ww, Wo, wb);

    (void)hipFuncSetAttribute(reinterpret_cast<const void*>(ntm_main),
                              hipFuncAttributeMaxDynamicSharedMemorySize, DLDS);

    hipLaunchKernelGGL(ntm_main, dim3(B_TOT / 2), dim3(1024), DLDS, stream,
                       x, wb, b1, b2, br, bw, bo, init_read, mem0, out);
}

// Round 5
// 9022.765 us; speedup vs baseline: 2.0904x; 1.0269x over previous
//
#include <hip/hip_runtime.h>
#include <stdint.h>

typedef unsigned short u16;
typedef unsigned int   u32;

// Problem dims
#define T_STEPS 256
#define B_TOT   512
#define EDIM    256
#define NSLOT   128
#define VDIM    256
#define ODIM    256

// Weights in d_ws, bf16 packed PAIR-ALONG-K: u32[(K/2)*C], entry (kp,c) =
// (W[2kp][c] lo16, W[2kp+1][c] hi16). Offsets in u32 units.
#define OFF_W1 0         // K=512 C=256 -> 65536
#define OFF_W2 65536     // K=256 C=256 -> 32768
#define OFF_WR 98304     // K=256 C=256 -> 32768
#define OFF_WW 131072    // K=256 C=512 -> 65536
#define OFF_WO 196608    // K=512 C=256 -> 65536
#define W_TOTAL_U32 262144

// LDS mem layout (1 batch row per block): 128 slots x 264 u16 (256 data + 8 pad)
#define USLOT 264
#define QSLOT 33                  // uint4 per slot
#define DLDS  (NSLOT * USLOT * 2) // 67584 bytes dynamic LDS

__device__ __forceinline__ float bflo(u32 u) { return __uint_as_float(u << 16); }
__device__ __forceinline__ float bfhi(u32 u) { return __uint_as_float(u & 0xffff0000u); }
__device__ __forceinline__ u32 f2bfbits(float f) {
    u32 a = __float_as_uint(f);
    return (a + 0x7fffu + ((a >> 16) & 1u)) >> 16;   // RNE
}
__device__ __forceinline__ u32 pkbf(float lo, float hi) {
    u32 a = __float_as_uint(lo), b = __float_as_uint(hi);
    a = a + 0x7fffu + ((a >> 16) & 1u);
    b = b + 0x7fffu + ((b >> 16) & 1u);
    return (a >> 16) | (b & 0xffff0000u);
}
// D = a.lo*b.lo + a.hi*b.hi + c  (bf16 inputs, fp32 accumulate) — V_DOT2_F32_BF16
__device__ __forceinline__ float dot2bf(u32 a, u32 b, float c) {
    float d;
    asm("v_dot2_f32_bf16 %0, %1, %2, %3" : "=v"(d) : "v"(a), "v"(b), "v"(c));
    return d;
}

// fp32 -> bf16 pair-along-K packer
__global__ void cvt_weights(const float* __restrict__ W1, const float* __restrict__ W2,
                            const float* __restrict__ Wr, const float* __restrict__ Ww,
                            const float* __restrict__ Wo, u32* __restrict__ dst) {
    int idx = blockIdx.x * 256 + threadIdx.x;     // u32 index
    const float* src; int local, lc;
    if      (idx < 65536)  { src = W1; local = idx;          lc = 8; }
    else if (idx < 98304)  { src = W2; local = idx - 65536;  lc = 8; }
    else if (idx < 131072) { src = Wr; local = idx - 98304;  lc = 8; }
    else if (idx < 196608) { src = Ww; local = idx - 131072; lc = 9; }
    else                   { src = Wo; local = idx - 196608; lc = 8; }
    const int C  = 1 << lc;
    const int kp = local >> lc, c = local & (C - 1);
    dst[idx] = pkbf(src[(2 * kp) * C + c], src[(2 * kp + 1) * C + c]);
}

// 1-row matvec, 512 threads. Thread owns cols (2jg, 2jg+1), k-slice s.
// src: bf16 pairs in LDS. W: u32 paired-K. Partials -> part (S*C fp32),
// barrier, finalize sums S slices. DST: 1 = LDS bf16 [c]; 2 = global fp32.
template<int K, int C, int DST, bool RELU>
__device__ __forceinline__ void matvec(const u32* __restrict__ W,
                                       const u16* __restrict__ srcB,
                                       const float* __restrict__ bias,
                                       float* __restrict__ part,
                                       u16* __restrict__ dstB,
                                       float* __restrict__ gout) {
    constexpr int G    = C / 2;             // 128 or 256
    constexpr int LG   = (G == 128) ? 7 : 8;
    constexpr int S    = 512 / G;           // 4 or 2
    constexpr int LENP = (K / 2) / S;       // kpairs per slice (32 or 64)
    const int tid = threadIdx.x;
    const int jg  = tid & (G - 1);
    const int s   = tid >> LG;

    float a0 = 0.f, a1 = 0.f;
    const uint2* Wp = reinterpret_cast<const uint2*>(W) + (size_t)(s * LENP) * G + jg;
    const u32*   ap = reinterpret_cast<const u32*>(srcB) + s * LENP;

#pragma unroll 2
    for (int kk = 0; kk < LENP; kk += 4) {
        uint2 w0 = Wp[(kk + 0) * G];
        uint2 w1 = Wp[(kk + 1) * G];
        uint2 w2 = Wp[(kk + 2) * G];
        uint2 w3 = Wp[(kk + 3) * G];
        uint4 a4 = *reinterpret_cast<const uint4*>(ap + kk);
        a0 = dot2bf(a4.x, w0.x, a0); a1 = dot2bf(a4.x, w0.y, a1);
        a0 = dot2bf(a4.y, w1.x, a0); a1 = dot2bf(a4.y, w1.y, a1);
        a0 = dot2bf(a4.z, w2.x, a0); a1 = dot2bf(a4.z, w2.y, a1);
        a0 = dot2bf(a4.w, w3.x, a0); a1 = dot2bf(a4.w, w3.y, a1);
    }
    reinterpret_cast<float2*>(part)[s * G + jg] = make_float2(a0, a1);
    __syncthreads();

    if (tid < C) {
        float v = bias[tid];
#pragma unroll
        for (int s2 = 0; s2 < S; ++s2) v += part[s2 * C + tid];
        if (RELU) v = fmaxf(v, 0.0f);
        if constexpr (DST == 1) dstB[tid] = (u16)f2bfbits(v);
        else                    gout[tid] = v;
    }
    if constexpr (DST != 2) __syncthreads();
}

__global__ __launch_bounds__(512, 4)
void ntm_main(const float* __restrict__ x, const u32* __restrict__ Wb,
              const float* __restrict__ b1, const float* __restrict__ b2,
              const float* __restrict__ br, const float* __restrict__ bw,
              const float* __restrict__ bo,
              const float* __restrict__ init_read, const float* __restrict__ mem0,
              float* __restrict__ out) {
    extern __shared__ u16 s_mem[];                 // 128 x 264 bf16 (padded)
    __shared__ __align__(16) float s_part[1024];   // matvec / pass2a partials
    __shared__ __align__(16) u16   s_cib[512];     // [x | r] bf16
    __shared__ __align__(16) u16   s_hb[256];      // h bf16
    __shared__ __align__(16) u16   s_crb[512];     // [co | r] bf16
    __shared__ __align__(16) u16   s_kvb[256];     // k bf16
    __shared__ __align__(16) u16   s_ovb[512];     // [kw | v] bf16
    __shared__ __align__(16) float s_dotr[128], s_dotw[128], s_mn2[128];
    __shared__ __align__(16) float s_wr[128], s_ww[128];

    const int tid = threadIdx.x;
    const int b   = blockIdx.x;
    uint4* memq = reinterpret_cast<uint4*>(s_mem);
    u32*   m32  = reinterpret_cast<u32*>(s_mem);

    // ---- init: mem0 -> LDS bf16 pairs, init_read -> ci r-slot ----
#pragma unroll 1
    for (int it = 0; it < 32; ++it) {
        int li = it * 512 + tid;                 // float2 index 0..16383
        int n = li >> 7, c = li & 127;           // c: u32 within slot
        float2 g = reinterpret_cast<const float2*>(mem0 + ((size_t)b << 15))[li];
        m32[n * (QSLOT * 4) + c] = pkbf(g.x, g.y);
    }
    if (tid < 128) {
        float2 g = reinterpret_cast<const float2*>(init_read + ((size_t)b << 8))[tid];
        reinterpret_cast<u32*>(s_cib)[128 + tid] = pkbf(g.x, g.y);
    }
    __syncthreads();

#pragma unroll 1
    for (int t = 0; t < T_STEPS; ++t) {
        // ---- load x_t -> bf16 pairs ----
        if (tid < 128) {
            float2 g = reinterpret_cast<const float2*>(
                x + (size_t)t * (B_TOT * EDIM) + (size_t)b * EDIM)[tid];
            reinterpret_cast<u32*>(s_cib)[tid] = pkbf(g.x, g.y);
        }
        __syncthreads();

        // ---- GEMM chain (dot2) ----
        matvec<512, 256, 1, true >(Wb + OFF_W1, s_cib, b1, s_part, s_hb,  nullptr);
        matvec<256, 256, 1, false>(Wb + OFF_W2, s_hb,  b2, s_part, s_crb, nullptr);
        matvec<256, 256, 1, false>(Wb + OFF_WR, s_crb, br, s_part, s_kvb, nullptr);
        matvec<256, 512, 1, false>(Wb + OFF_WW, s_crb, bw, s_part, s_ovb, nullptr);

        // ---- pass1: dr=k.mem, dw=kw.mem, s2=|mem|^2 ; thread = (n, vq) ----
        {
            const int n = tid >> 2, vq = tid & 3;
            const uint4* mq  = memq + n * QSLOT + vq * 8;
            const uint4* kq  = reinterpret_cast<const uint4*>(s_kvb) + vq * 8;
            const uint4* kwq = reinterpret_cast<const uint4*>(s_ovb) + vq * 8;
            float dr = 0.f, dw = 0.f, s2 = 0.f;
#pragma unroll
            for (int i = 0; i < 8; ++i) {
                uint4 m = mq[i], ka = kq[i], kb = kwq[i];
                dr = dot2bf(m.x, ka.x, dr); dr = dot2bf(m.y, ka.y, dr);
                dr = dot2bf(m.z, ka.z, dr); dr = dot2bf(m.w, ka.w, dr);
                dw = dot2bf(m.x, kb.x, dw); dw = dot2bf(m.y, kb.y, dw);
                dw = dot2bf(m.z, kb.z, dw); dw = dot2bf(m.w, kb.w, dw);
                s2 = dot2bf(m.x, m.x, s2);  s2 = dot2bf(m.y, m.y, s2);
                s2 = dot2bf(m.z, m.z, s2);  s2 = dot2bf(m.w, m.w, s2);
            }
            dr += __shfl_xor(dr, 1); dr += __shfl_xor(dr, 2);
            dw += __shfl_xor(dw, 1); dw += __shfl_xor(dw, 2);
            s2 += __shfl_xor(s2, 1); s2 += __shfl_xor(s2, 2);
            if (vq == 0) { s_dotr[n] = dr; s_dotw[n] = dw; s_mn2[n] = s2; }
        }
        __syncthreads();

        // ---- softmax (cosine addressing), one wave per key ----
        if (tid < 128) {
            const int key = tid >> 6, lane = tid & 63;
            const uint2* kv2 = key ? reinterpret_cast<const uint2*>(s_ovb)
                                   : reinterpret_cast<const uint2*>(s_kvb);
            uint2 kk = kv2[lane];
            float q = dot2bf(kk.x, kk.x, 0.f);
            q = dot2bf(kk.y, kk.y, q);
#pragma unroll
            for (int m = 1; m < 64; m <<= 1) q += __shfl_xor(q, m);
            float kn = fmaxf(sqrtf(q), 1e-8f);
            const float* dot = key ? s_dotw : s_dotr;
            int n0 = lane, n1 = lane + 64;
            float mn0 = fmaxf(sqrtf(s_mn2[n0]), 1e-8f);
            float mn1 = fmaxf(sqrtf(s_mn2[n1]), 1e-8f);
            float av0 = dot[n0] / (kn * mn0);
            float av1 = dot[n1] / (kn * mn1);
            float mx = fmaxf(av0, av1);
#pragma unroll
            for (int m = 1; m < 64; m <<= 1) mx = fmaxf(mx, __shfl_xor(mx, m));
            float e0 = __expf(av0 - mx), e1 = __expf(av1 - mx);
            float sm = e0 + e1;
#pragma unroll
            for (int m = 1; m < 64; m <<= 1) sm += __shfl_xor(sm, m);
            float inv = 1.0f / sm;
            float* wdst = key ? s_ww : s_wr;
            wdst[n0] = e0 * inv;
            wdst[n1] = e1 * inv;
        }
        __syncthreads();

        // ---- pass2a: r = sum_n w[n]*mem[n,:]; thread = (ns: 32 slots, vc: 1 u32) ----
        {
            const int ns = tid >> 7, vc = tid & 127;
            float r0 = 0.f, r1 = 0.f;
            const float* wp = s_wr + ns * 32;
            const int base = (ns * 32) * (QSLOT * 4) + vc;
#pragma unroll 4
            for (int j = 0; j < 32; ++j) {
                u32 m = m32[base + j * (QSLOT * 4)];
                float wj = wp[j];
                r0 = fmaf(bflo(m), wj, r0);
                r1 = fmaf(bfhi(m), wj, r1);
            }
            reinterpret_cast<float2*>(s_part)[ns * 128 + vc] = make_float2(r0, r1);
        }
        __syncthreads();
        if (tid < 256) {   // finalize r -> ci/cr r-slots (bf16)
            float v = s_part[tid] + s_part[256 + tid] + s_part[512 + tid] + s_part[768 + tid];
            u16 hb = (u16)f2bfbits(v);
            s_cib[256 + tid] = hb;
            s_crb[256 + tid] = hb;
        }
        // no barrier needed before pass2b (disjoint buffers); pass2b's own barrier orders all

        // ---- pass2b: mem += ww[n]*v ; thread = (n, vq) ----
        {
            const int n = tid >> 2, vq = tid & 3;
            uint4* mq = memq + n * QSLOT + vq * 8;
            const uint4* vvq = reinterpret_cast<const uint4*>(s_ovb) + 32 + vq * 8;
            const float ww = s_ww[n];
#pragma unroll
            for (int i = 0; i < 8; ++i) {
                uint4 m = mq[i], vv = vvq[i];
                u32* pm = reinterpret_cast<u32*>(&m);
                const u32* pv = reinterpret_cast<const u32*>(&vv);
#pragma unroll
                for (int q = 0; q < 4; ++q) {
                    float o0 = fmaf(bflo(pv[q]), ww, bflo(pm[q]));
                    float o1 = fmaf(bfhi(pv[q]), ww, bfhi(pm[q]));
                    pm[q] = pkbf(o0, o1);
                }
                mq[i] = m;
            }
        }
        __syncthreads();

        // ---- out_t = [co | r] @ Wo + bo -> global ----
        matvec<512, 256, 2, false>(Wb + OFF_WO, s_crb, bo, s_part, nullptr,
                                   out + (size_t)t * (B_TOT * ODIM) + (size_t)b * ODIM);
    }
}

extern "C" void kernel_launch(void* const* d_in, const int* in_sizes, int n_in,
                              void* d_out, int out_size, void* d_ws, size_t ws_size,
                              hipStream_t stream) {
    (void)in_sizes; (void)n_in; (void)out_size; (void)ws_size;
    const float* x         = (const float*)d_in[0];
    const float* W1        = (const float*)d_in[1];
    const float* b1        = (const float*)d_in[2];
    const float* W2        = (const float*)d_in[3];
    const float* b2        = (const float*)d_in[4];
    const float* Wr        = (const float*)d_in[5];
    const float* br        = (const float*)d_in[6];
    const float* Ww        = (const float*)d_in[7];
    const float* bw        = (const float*)d_in[8];
    const float* Wo        = (const float*)d_in[9];
    const float* bo        = (const float*)d_in[10];
    const float* init_read = (const float*)d_in[11];
    const float* mem0      = (const float*)d_in[12];
    float* out = (float*)d_out;
    u32* wb = (u32*)d_ws;

    hipLaunchKernelGGL(cvt_weights, dim3(W_TOTAL_U32 / 256), dim3(256), 0, stream,
                       W1, W2, Wr, Ww, Wo, wb);

    (void)hipFuncSetAttribute(reinterpret_cast<const void*>(ntm_main),
                              hipFuncAttributeMaxDynamicSharedMemorySize, DLDS);

    hipLaunchKernelGGL(ntm_main, dim3(B_TOT), dim3(512), DLDS, stream,
                       x, wb, b1, b2, br, bw, bo, init_read, mem0, out);
}